// Round 2
// baseline (551.439 us; speedup 1.0000x reference)
//
#include <hip/hip_runtime.h>

#define NN 8
#define CC 64
#define HH 256
#define WW 256
#define GG 8
#define CPG (CC / GG)
#define EPSF 1e-5f
#define SLABS 8                      // k_stats: H split into 8 slabs of 32 rows
#define RPW 8                        // rows per wave in k_stats

// conv for one output row given the 3 input rows + their precomputed halos
__device__ __forceinline__ float4 conv_row(
    const float4& a, float la, float ra,
    const float4& b, float lb, float rb,
    const float4& c, float lc, float rc,
    const float* __restrict__ w)
{
    float4 o;
    o.x = w[0] * la  + w[1] * a.x + w[2] * a.y
        + w[3] * lb  + w[4] * b.x + w[5] * b.y
        + w[6] * lc  + w[7] * c.x + w[8] * c.y;
    o.y = w[0] * a.x + w[1] * a.y + w[2] * a.z
        + w[3] * b.x + w[4] * b.y + w[5] * b.z
        + w[6] * c.x + w[7] * c.y + w[8] * c.z;
    o.z = w[0] * a.y + w[1] * a.z + w[2] * a.w
        + w[3] * b.y + w[4] * b.z + w[5] * b.w
        + w[6] * c.y + w[7] * c.z + w[8] * c.w;
    o.w = w[0] * a.z + w[1] * a.w + w[2] * ra
        + w[3] * b.z + w[4] * b.w + w[5] * rb
        + w[6] * c.z + w[7] * c.w + w[8] * rc;
    return o;
}

// Pass 1: per-(n,c,slab) block; wave = 8 consecutive rows of one channel.
// 10 rows preloaded to registers -> 10 independent loads in flight per thread.
__global__ __launch_bounds__(256) void k_stats(
    const float* __restrict__ x, const float* __restrict__ wt,
    float* __restrict__ sums)
{
    int b    = blockIdx.x;                 // n * CC * SLABS + c * SLABS + slab
    int n    = b / (CC * SLABS);
    int c    = (b / SLABS) % CC;
    int slab = b % SLABS;
    int wid  = threadIdx.x >> 6;
    int lane = threadIdx.x & 63;
    int r0   = slab * (HH / SLABS) + wid * RPW;
    int w0   = lane << 2;

    const float* xc = x + ((size_t)n * CC + c) * HH * WW;

    float w[9];
#pragma unroll
    for (int k = 0; k < 9; ++k) w[k] = wt[k * CC + c];   // wave-uniform -> scalar

    float4 rows[RPW + 2];
#pragma unroll
    for (int i = 0; i < RPW + 2; ++i) {
        int r = r0 - 1 + i;
        if (r >= 0 && r < HH)                            // uniform; only edges
            rows[i] = *(const float4*)(xc + (size_t)r * WW + w0);
        else
            rows[i] = make_float4(0.f, 0.f, 0.f, 0.f);
    }

    float L[RPW + 2], R[RPW + 2];
#pragma unroll
    for (int i = 0; i < RPW + 2; ++i) {
        float l = __shfl_up(rows[i].w, 1);
        float r = __shfl_down(rows[i].x, 1);
        L[i] = (lane == 0)  ? 0.f : l;
        R[i] = (lane == 63) ? 0.f : r;
    }

    float s = 0.f, sq = 0.f;
#pragma unroll
    for (int i = 0; i < RPW; ++i) {
        float4 o = conv_row(rows[i],     L[i],     R[i],
                            rows[i + 1], L[i + 1], R[i + 1],
                            rows[i + 2], L[i + 2], R[i + 2], w);
        s  += (o.x + o.y) + (o.z + o.w);
        sq += (o.x * o.x + o.y * o.y) + (o.z * o.z + o.w * o.w);
    }

#pragma unroll
    for (int off = 32; off; off >>= 1) {
        s  += __shfl_down(s, off);
        sq += __shfl_down(sq, off);
    }
    if (lane == 0) {
        int g = c / CPG;
        atomicAdd(&sums[(n * GG + g) * 2 + 0], s);
        atomicAdd(&sums[(n * GG + g) * 2 + 1], sq);
    }
}

__global__ void k_finalize(const float* __restrict__ sums, float* __restrict__ mr)
{
    int i = threadIdx.x;  // 0..63 (n,g) pairs
    float s = sums[i * 2 + 0], sq = sums[i * 2 + 1];
    const float inv = 1.f / (float)(CPG * HH * WW);
    float mean = s * inv;
    float var  = sq * inv - mean * mean;
    mr[i * 2 + 0] = mean;
    mr[i * 2 + 1] = rsqrtf(var + EPSF);
}

__device__ __forceinline__ float actres(float v, float mean, float rstd)
{
    float xn = (v - mean) * rstd;
    xn = fminf(fmaxf(xn, -15.f), 15.f);
    float e2 = __expf(2.f * xn);
    float th = __fdividef(e2 - 1.f, e2 + 1.f);
    // tanh in (-1,1) => th+3 in (2,4) => hardswish clamp is identity
    float hs = th * (th + 3.f) * (1.f / 6.f);
    return v + hs;
}

// Pass 2: block = one (n,h) row; 4 waves x 16 channels; LDS-reduce exp sums;
// every wave writes its 16 channel-rows of the broadcast lse.
__global__ __launch_bounds__(256) void k_main(
    const float* __restrict__ x, const float* __restrict__ wt,
    const float* __restrict__ mr, float* __restrict__ out)
{
    int b    = blockIdx.x;            // n * HH + h
    int n    = b >> 8;
    int h    = b & (HH - 1);
    int wid  = threadIdx.x >> 6;
    int lane = threadIdx.x & 63;
    int w0   = lane << 2;

    const float* xn = x + (size_t)n * CC * HH * WW;

    float4 acc = make_float4(0.f, 0.f, 0.f, 0.f);

#pragma unroll
    for (int gi = 0; gi < 2; ++gi) {
        int g = wid * 2 + gi;
        float mean = mr[(n * GG + g) * 2 + 0];
        float rstd = mr[(n * GG + g) * 2 + 1];
#pragma unroll
        for (int ci = 0; ci < CPG; ++ci) {
            int c = g * CPG + ci;
            const float* xc = xn + (size_t)c * HH * WW;
            float w[9];
#pragma unroll
            for (int k = 0; k < 9; ++k) w[k] = wt[k * CC + c];

            float4 rz = *(const float4*)(xc + (size_t)h * WW + w0);
            float4 rm = make_float4(0.f, 0.f, 0.f, 0.f);
            float4 rp = make_float4(0.f, 0.f, 0.f, 0.f);
            if (h > 0)      rm = *(const float4*)(xc + (size_t)(h - 1) * WW + w0);
            if (h < HH - 1) rp = *(const float4*)(xc + (size_t)(h + 1) * WW + w0);

            float lm = __shfl_up(rm.w, 1), lz = __shfl_up(rz.w, 1), lp = __shfl_up(rp.w, 1);
            float hm = __shfl_down(rm.x, 1), hz = __shfl_down(rz.x, 1), hp = __shfl_down(rp.x, 1);
            if (lane == 0)  { lm = 0.f; lz = 0.f; lp = 0.f; }
            if (lane == 63) { hm = 0.f; hz = 0.f; hp = 0.f; }

            float4 o = conv_row(rm, lm, hm, rz, lz, hz, rp, lp, hp, w);
            acc.x += __expf(actres(o.x, mean, rstd));
            acc.y += __expf(actres(o.y, mean, rstd));
            acc.z += __expf(actres(o.z, mean, rstd));
            acc.w += __expf(actres(o.w, mean, rstd));
        }
    }

    __shared__ float4 lds[4][64];
    lds[wid][lane] = acc;
    __syncthreads();
    float4 a0 = lds[0][lane], a1 = lds[1][lane], a2 = lds[2][lane], a3 = lds[3][lane];
    float4 t = make_float4(a0.x + a1.x + a2.x + a3.x,
                           a0.y + a1.y + a2.y + a3.y,
                           a0.z + a1.z + a2.z + a3.z,
                           a0.w + a1.w + a2.w + a3.w);
    float4 lse = make_float4(logf(t.x), logf(t.y), logf(t.z), logf(t.w));

    float* op = out + (((size_t)(n * CC + wid * 16)) * HH + h) * WW + w0;
#pragma unroll
    for (int k = 0; k < 16; ++k) {
        *(float4*)op = lse;
        op += (size_t)HH * WW;
    }
}

extern "C" void kernel_launch(void* const* d_in, const int* in_sizes, int n_in,
                              void* d_out, int out_size, void* d_ws, size_t ws_size,
                              hipStream_t stream)
{
    const float* x  = (const float*)d_in[0];
    const float* wt = (const float*)d_in[1];
    float* out  = (float*)d_out;
    float* sums = (float*)d_ws;
    float* mr   = sums + 128;

    hipMemsetAsync(sums, 0, 128 * sizeof(float), stream);

    k_stats<<<NN * CC * SLABS, 256, 0, stream>>>(x, wt, sums);      // 4096 blocks
    k_finalize<<<1, 64, 0, stream>>>(sums, mr);
    k_main<<<NN * HH, 256, 0, stream>>>(x, wt, mr, out);            // 2048 blocks
}

// Round 4
// 272.388 us; speedup vs baseline: 2.0245x; 2.0245x over previous
//
#include <hip/hip_runtime.h>

#define NN 8
#define CC 64
#define HH 256
#define WW 256
#define GG 8
#define CPG (CC / GG)
#define EPSF 1e-5f
#define SLABS 8                      // H split into 8 slabs of 32 rows
#define RPW 8                        // rows per wave

typedef _Float16 h4 __attribute__((ext_vector_type(4)));
typedef float    f4 __attribute__((ext_vector_type(4)));

// conv for one output row given 3 input rows + their precomputed halo scalars
__device__ __forceinline__ float4 conv_row(
    const float4& a, float la, float ra,
    const float4& b, float lb, float rb,
    const float4& c, float lc, float rc,
    const float* __restrict__ w)
{
    float4 o;
    o.x = w[0] * la  + w[1] * a.x + w[2] * a.y
        + w[3] * lb  + w[4] * b.x + w[5] * b.y
        + w[6] * lc  + w[7] * c.x + w[8] * c.y;
    o.y = w[0] * a.x + w[1] * a.y + w[2] * a.z
        + w[3] * b.x + w[4] * b.y + w[5] * b.z
        + w[6] * c.x + w[7] * c.y + w[8] * c.z;
    o.z = w[0] * a.y + w[1] * a.z + w[2] * a.w
        + w[3] * b.y + w[4] * b.z + w[5] * b.w
        + w[6] * c.y + w[7] * c.z + w[8] * c.w;
    o.w = w[0] * a.z + w[1] * a.w + w[2] * ra
        + w[3] * b.z + w[4] * b.w + w[5] * rb
        + w[6] * c.z + w[7] * c.w + w[8] * rc;
    return o;
}

// ---------------------------------------------------------------------------
// Pass A: depthwise conv -> fp16 store to ws + per-(n,g) sum/sumsq stats.
// block = (n, c, slab); wave = 8 consecutive rows of one channel.
// ---------------------------------------------------------------------------
__global__ __launch_bounds__(256, 4) void k_conv(
    const float* __restrict__ x, const float* __restrict__ wt,
    _Float16* __restrict__ conv, float* __restrict__ sums)
{
    int b    = blockIdx.x;                 // n*(CC*SLABS) + c*SLABS + slab
    int n    = b / (CC * SLABS);
    int c    = (b / SLABS) % CC;
    int slab = b % SLABS;
    int wid  = threadIdx.x >> 6;
    int lane = threadIdx.x & 63;
    int r0   = slab * (HH / SLABS) + wid * RPW;
    int w0   = lane << 2;

    const float* xc = x    + ((size_t)n * CC + c) * HH * WW;
    _Float16*    oc = conv + ((size_t)n * CC + c) * HH * WW;

    float w[9];
#pragma unroll
    for (int k = 0; k < 9; ++k) w[k] = wt[k * CC + c];   // block-uniform

    float4 rows[RPW + 2];
#pragma unroll
    for (int i = 0; i < RPW + 2; ++i) {
        int r = r0 - 1 + i;
        if (r >= 0 && r < HH)
            rows[i] = *(const float4*)(xc + (size_t)r * WW + w0);
        else
            rows[i] = make_float4(0.f, 0.f, 0.f, 0.f);
    }

    float L[RPW + 2], R[RPW + 2];
#pragma unroll
    for (int i = 0; i < RPW + 2; ++i) {
        float l = __shfl_up(rows[i].w, 1);
        float r = __shfl_down(rows[i].x, 1);
        L[i] = (lane == 0)  ? 0.f : l;
        R[i] = (lane == 63) ? 0.f : r;
    }

    float s = 0.f, sq = 0.f;
#pragma unroll
    for (int i = 0; i < RPW; ++i) {
        float4 o = conv_row(rows[i],     L[i],     R[i],
                            rows[i + 1], L[i + 1], R[i + 1],
                            rows[i + 2], L[i + 2], R[i + 2], w);
        s  += (o.x + o.y) + (o.z + o.w);
        sq += (o.x * o.x + o.y * o.y) + (o.z * o.z + o.w * o.w);
        h4 hv;
        hv[0] = (_Float16)o.x; hv[1] = (_Float16)o.y;
        hv[2] = (_Float16)o.z; hv[3] = (_Float16)o.w;
        *(h4*)(oc + (size_t)(r0 + i) * WW + w0) = hv;
    }

#pragma unroll
    for (int off = 32; off; off >>= 1) {
        s  += __shfl_down(s, off);
        sq += __shfl_down(sq, off);
    }
    __shared__ float red[8];
    if (lane == 0) { red[wid * 2] = s; red[wid * 2 + 1] = sq; }
    __syncthreads();
    if (threadIdx.x == 0) {
        float S = red[0] + red[2] + red[4] + red[6];
        float Q = red[1] + red[3] + red[5] + red[7];
        int g = c / CPG;
        atomicAdd(&sums[(n * GG + g) * 2 + 0], S);
        atomicAdd(&sums[(n * GG + g) * 2 + 1], Q);
    }
}

__global__ void k_finalize(const float* __restrict__ sums, float* __restrict__ mr)
{
    int i = threadIdx.x;  // 0..63 (n,g) pairs
    float s = sums[i * 2 + 0], sq = sums[i * 2 + 1];
    const float inv = 1.f / (float)(CPG * HH * WW);
    float mean = s * inv;
    float var  = sq * inv - mean * mean;
    mr[i * 2 + 0] = mean;
    mr[i * 2 + 1] = rsqrtf(var + EPSF);
}

// ---------------------------------------------------------------------------
// Pass B: read fp16 conv rows (h only, no halo), normalize+tanh+hswish+res,
// exp-accumulate over channels, LSE, broadcast store (nontemporal).
// block = one (n,h) row; 4 waves x 16 channels; LDS reduce.
// ---------------------------------------------------------------------------
__global__ __launch_bounds__(256, 4) void k_lse(
    const _Float16* __restrict__ conv, const float* __restrict__ mr,
    float* __restrict__ out)
{
    int b    = blockIdx.x;            // n*HH + h
    int n    = b >> 8;
    int h    = b & (HH - 1);
    int wid  = threadIdx.x >> 6;
    int lane = threadIdx.x & 63;
    int w0   = lane << 2;

    const _Float16* cb = conv + (size_t)n * CC * HH * WW + (size_t)h * WW + w0;

    float acca[4] = {0.f, 0.f, 0.f, 0.f};

#pragma unroll
    for (int gi = 0; gi < 2; ++gi) {
        int g = wid * 2 + gi;
        float mean = mr[(n * GG + g) * 2 + 0];
        float rstd = mr[(n * GG + g) * 2 + 1];
        float s2   = 2.f * rstd;
        const _Float16* cp = cb + (size_t)(g * CPG) * HH * WW;
#pragma unroll
        for (int ci = 0; ci < CPG; ++ci) {
            h4 hv = *(const h4*)(cp + (size_t)ci * HH * WW);
#pragma unroll
            for (int j = 0; j < 4; ++j) {
                float v  = (float)hv[j];
                float t0 = fminf((v - mean) * s2, 55.f);   // tanh saturation clamp
                float e2 = __expf(t0);
                float r  = __builtin_amdgcn_rcpf(e2 + 1.f);
                float th = (e2 - 1.f) * r;                 // tanh in (-1,1)
                // hardswish clamp is identity for th+3 in (2,4)
                float hs = th * (th + 3.f) * (1.f / 6.f);
                acca[j] += __expf(v + hs);                 // residual + exp
            }
        }
    }

    __shared__ float4 lds[4][64];
    lds[wid][lane] = make_float4(acca[0], acca[1], acca[2], acca[3]);
    __syncthreads();
    float4 a0 = lds[0][lane], a1 = lds[1][lane], a2 = lds[2][lane], a3 = lds[3][lane];
    f4 lse;
    lse.x = __logf(a0.x + a1.x + a2.x + a3.x);
    lse.y = __logf(a0.y + a1.y + a2.y + a3.y);
    lse.z = __logf(a0.z + a1.z + a2.z + a3.z);
    lse.w = __logf(a0.w + a1.w + a2.w + a3.w);

    float* op = out + (((size_t)(n * CC + wid * 16)) * HH + h) * WW + w0;
#pragma unroll
    for (int k = 0; k < 16; ++k) {
        __builtin_nontemporal_store(lse, (f4*)op);   // don't evict conv from L3
        op += (size_t)HH * WW;
    }
}

// ---------------------------------------------------------------------------
// Fallback path (ws too small): recompute conv in pass 2.
// ---------------------------------------------------------------------------
__global__ __launch_bounds__(256) void k_stats_rc(
    const float* __restrict__ x, const float* __restrict__ wt,
    float* __restrict__ sums)
{
    int b    = blockIdx.x;
    int n    = b / (CC * SLABS);
    int c    = (b / SLABS) % CC;
    int slab = b % SLABS;
    int wid  = threadIdx.x >> 6;
    int lane = threadIdx.x & 63;
    int r0   = slab * (HH / SLABS) + wid * RPW;
    int w0   = lane << 2;

    const float* xc = x + ((size_t)n * CC + c) * HH * WW;

    float w[9];
#pragma unroll
    for (int k = 0; k < 9; ++k) w[k] = wt[k * CC + c];

    float4 rows[RPW + 2];
#pragma unroll
    for (int i = 0; i < RPW + 2; ++i) {
        int r = r0 - 1 + i;
        if (r >= 0 && r < HH)
            rows[i] = *(const float4*)(xc + (size_t)r * WW + w0);
        else
            rows[i] = make_float4(0.f, 0.f, 0.f, 0.f);
    }
    float L[RPW + 2], R[RPW + 2];
#pragma unroll
    for (int i = 0; i < RPW + 2; ++i) {
        float l = __shfl_up(rows[i].w, 1);
        float r = __shfl_down(rows[i].x, 1);
        L[i] = (lane == 0)  ? 0.f : l;
        R[i] = (lane == 63) ? 0.f : r;
    }
    float s = 0.f, sq = 0.f;
#pragma unroll
    for (int i = 0; i < RPW; ++i) {
        float4 o = conv_row(rows[i], L[i], R[i], rows[i+1], L[i+1], R[i+1],
                            rows[i+2], L[i+2], R[i+2], w);
        s  += (o.x + o.y) + (o.z + o.w);
        sq += (o.x * o.x + o.y * o.y) + (o.z * o.z + o.w * o.w);
    }
#pragma unroll
    for (int off = 32; off; off >>= 1) {
        s  += __shfl_down(s, off);
        sq += __shfl_down(sq, off);
    }
    if (lane == 0) {
        int g = c / CPG;
        atomicAdd(&sums[(n * GG + g) * 2 + 0], s);
        atomicAdd(&sums[(n * GG + g) * 2 + 1], sq);
    }
}

__global__ __launch_bounds__(256) void k_main_rc(
    const float* __restrict__ x, const float* __restrict__ wt,
    const float* __restrict__ mr, float* __restrict__ out)
{
    int b    = blockIdx.x;
    int n    = b >> 8;
    int h    = b & (HH - 1);
    int wid  = threadIdx.x >> 6;
    int lane = threadIdx.x & 63;
    int w0   = lane << 2;

    const float* xn = x + (size_t)n * CC * HH * WW;
    float acca[4] = {0.f, 0.f, 0.f, 0.f};

#pragma unroll 1
    for (int gi = 0; gi < 2; ++gi) {
        int g = wid * 2 + gi;
        float mean = mr[(n * GG + g) * 2 + 0];
        float rstd = mr[(n * GG + g) * 2 + 1];
        float s2   = 2.f * rstd;
#pragma unroll 1
        for (int ci = 0; ci < CPG; ++ci) {
            int c = g * CPG + ci;
            const float* xc = xn + (size_t)c * HH * WW;
            float w[9];
#pragma unroll
            for (int k = 0; k < 9; ++k) w[k] = wt[k * CC + c];

            float4 rz = *(const float4*)(xc + (size_t)h * WW + w0);
            float4 rm = make_float4(0.f, 0.f, 0.f, 0.f);
            float4 rp = make_float4(0.f, 0.f, 0.f, 0.f);
            if (h > 0)      rm = *(const float4*)(xc + (size_t)(h - 1) * WW + w0);
            if (h < HH - 1) rp = *(const float4*)(xc + (size_t)(h + 1) * WW + w0);

            float lm = __shfl_up(rm.w, 1), lz = __shfl_up(rz.w, 1), lp = __shfl_up(rp.w, 1);
            float hm = __shfl_down(rm.x, 1), hz = __shfl_down(rz.x, 1), hp = __shfl_down(rp.x, 1);
            if (lane == 0)  { lm = 0.f; lz = 0.f; lp = 0.f; }
            if (lane == 63) { hm = 0.f; hz = 0.f; hp = 0.f; }

            float4 o = conv_row(rm, lm, hm, rz, lz, hz, rp, lp, hp, w);
            float ov[4] = {o.x, o.y, o.z, o.w};
#pragma unroll
            for (int j = 0; j < 4; ++j) {
                float v  = ov[j];
                float t0 = fminf((v - mean) * s2, 55.f);
                float e2 = __expf(t0);
                float r  = __builtin_amdgcn_rcpf(e2 + 1.f);
                float th = (e2 - 1.f) * r;
                float hs = th * (th + 3.f) * (1.f / 6.f);
                acca[j] += __expf(v + hs);
            }
        }
    }

    __shared__ float4 lds[4][64];
    lds[wid][lane] = make_float4(acca[0], acca[1], acca[2], acca[3]);
    __syncthreads();
    float4 a0 = lds[0][lane], a1 = lds[1][lane], a2 = lds[2][lane], a3 = lds[3][lane];
    f4 lse;
    lse.x = __logf(a0.x + a1.x + a2.x + a3.x);
    lse.y = __logf(a0.y + a1.y + a2.y + a3.y);
    lse.z = __logf(a0.z + a1.z + a2.z + a3.z);
    lse.w = __logf(a0.w + a1.w + a2.w + a3.w);

    float* op = out + (((size_t)(n * CC + wid * 16)) * HH + h) * WW + w0;
#pragma unroll
    for (int k = 0; k < 16; ++k) {
        __builtin_nontemporal_store(lse, (f4*)op);
        op += (size_t)HH * WW;
    }
}

extern "C" void kernel_launch(void* const* d_in, const int* in_sizes, int n_in,
                              void* d_out, int out_size, void* d_ws, size_t ws_size,
                              hipStream_t stream)
{
    const float* x  = (const float*)d_in[0];
    const float* wt = (const float*)d_in[1];
    float* out  = (float*)d_out;
    float* sums = (float*)d_ws;        // 128 floats: (n,g) x {sum, sumsq}
    float* mr   = sums + 128;          // 128 floats: (n,g) x {mean, rstd}

    const size_t convOff = 1024;       // bytes; keep sums/mr in front
    const size_t need = convOff + (size_t)NN * CC * HH * WW * sizeof(_Float16);

    (void)hipMemsetAsync(sums, 0, 128 * sizeof(float), stream);

    if (ws_size >= need) {
        _Float16* conv = (_Float16*)((char*)d_ws + convOff);
        k_conv<<<NN * CC * SLABS, 256, 0, stream>>>(x, wt, conv, sums);   // 4096 blocks
        k_finalize<<<1, 64, 0, stream>>>(sums, mr);
        k_lse<<<NN * HH, 256, 0, stream>>>(conv, mr, out);                // 2048 blocks
    } else {
        k_stats_rc<<<NN * CC * SLABS, 256, 0, stream>>>(x, wt, sums);
        k_finalize<<<1, 64, 0, stream>>>(sums, mr);
        k_main_rc<<<NN * HH, 256, 0, stream>>>(x, wt, mr, out);
    }
}